// Round 7
// baseline (103.027 us; speedup 1.0000x reference)
//
#include <hip/hip_runtime.h>

// DNA transport NEGF: per (b,e) invert A = (E*I - H) + i*diag(0.5*(gL+gR)),
// DOS = -Im tr(Gr), T = sum_ij gL_i gR_j |Gr_ij|^2, plus H scatter output.
//
// Lane j of a 20-lane subgroup owns column j of A (in-place Gauss-Jordan ->
// same registers end as column j of Gr). 3 subgroups/wave, 4 waves/block.
// Grid = 1024 batches x 9 chunks (12 energies each, flat).
//
// SYMMETRY BROADCAST (R3): no-pivot GJ on complex-symmetric A preserves
// M[i][j] = sigma*M[j][i] (sigma=-1 iff exactly one of i,j processed), so
// the pivot column is readable from each lane's own col[k]: one wave-wide
// ds_write_b64 + 10 broadcast ds_read_b128 per step. Signs fold into FMAs.
//
// FORCED v_pk_fma_f32 (R5): inline asm, signs + [tu.y,tu.x] swap folded into
// VOP3P op_sel/neg modifiers -> exactly 2 v_pk_fma_f32 per row.
//
// OCCUPANCY CAP (R6): R4/R5 showed VGPR_Count=36 -- the allocator chases
// 8 waves/SIMD (64-reg budget) and spills col[] to AGPRs; each update then
// pays v_accvgpr_read/write shuttles (~76 instr/step, half the VALU time).
// amdgpu_waves_per_eu(2,4) caps the target at 4 waves/SIMD (128-reg budget):
// col[40] + q[40] + misc ~110 fits -> no AGPR traffic. Measured occupancy
// was ~60% anyway, so capping at 50% costs little latency hiding.
//
// R1 lesson: ds_bpermute (40 DS/step) loses. R2 lesson: tight occupancy
// targets remat/spill the hot arrays -> DS- or move-bound.
//
// No pivoting: imag(x^* A x) > 0 for all leading blocks => pivots bounded
// below by min_i 0.5(gL_i+gR_i). Stable in fp32 (R0-R5: absmax <= 3.9e-3).

typedef float f32x2 __attribute__((ext_vector_type(2)));
typedef float f32x4 __attribute__((ext_vector_type(4)));

#define H_N   20
#define NE    100
#define T_OFF 0
#define D_OFF 102400
#define H_OFF 204800

__device__ __forceinline__ int triIdx(int i, int j) {  // i <= j, row-major triu
    return i * H_N - ((i * (i - 1)) >> 1) + (j - i);
}

// col -= (+s)*tu : lo: c.x += s.y*tu.y - s.x*tu.x ; hi: c.y += -s.y*tu.x - s.x*tu.y
__device__ __forceinline__ void upd_pos(f32x2& c, f32x2 s, f32x2 tu) {
    asm("v_pk_fma_f32 %0, %1, %2, %0 op_sel:[1,1,0] op_sel_hi:[1,0,1] neg_hi:[1,0,0]\n\t"
        "v_pk_fma_f32 %0, %1, %2, %0 op_sel_hi:[0,1,1] neg_lo:[1,0,0] neg_hi:[1,0,0]"
        : "+v"(c) : "v"(s), "v"(tu));
}

// col -= (-s)*tu : lo: c.x += -s.y*tu.y + s.x*tu.x ; hi: c.y += s.y*tu.x + s.x*tu.y
__device__ __forceinline__ void upd_neg(f32x2& c, f32x2 s, f32x2 tu) {
    asm("v_pk_fma_f32 %0, %1, %2, %0 op_sel:[1,1,0] op_sel_hi:[1,0,1] neg_lo:[1,0,0]\n\t"
        "v_pk_fma_f32 %0, %1, %2, %0 op_sel_hi:[0,1,1]"
        : "+v"(c) : "v"(s), "v"(tu));
}

__global__ __launch_bounds__(256)
__attribute__((amdgpu_waves_per_eu(2, 4)))
void negf_all(const float* __restrict__ tri,
              const float* __restrict__ GL,
              const float* __restrict__ GR,
              float* __restrict__ out)
{
    __shared__ float Hcm[400];          // column-major: Hcm[c*20 + r] = H[r][c]
    __shared__ float sgL[H_N], sgR[H_N];
    __shared__ f32x4 stage[12][10];     // per-subgroup pivot-column broadcast

    const int blk   = blockIdx.x;
    const int b     = blk / 9;
    const int chunk = blk - b * 9;
    const int tid   = threadIdx.x;

    // ---- stage H (column-major) + gammas into LDS ----
    const float* triB = tri + b * 210;
    #pragma unroll
    for (int u0 = 0; u0 < 2; ++u0) {
        int u = tid + u0 * 256;
        if (u < 400) {
            int c = u / 20, r = u - c * 20;
            int lo = r < c ? r : c;
            int hi = r < c ? c : r;
            Hcm[u] = triB[triIdx(lo, hi)];
        }
    }
    if (tid < H_N) {
        sgL[tid] = GL[b * H_N + tid];
        sgR[tid] = GR[b * H_N + tid];
    }
    __syncthreads();

    // ---- H output (row-major), exact copy of inputs; one block per b ----
    if (chunk == 0) {
        #pragma unroll
        for (int u0 = 0; u0 < 2; ++u0) {
            int u = tid + u0 * 256;
            if (u < 400) {
                int r = u / 20, c = u - r * 20;
                out[H_OFF + b * 400 + u] = Hcm[c * 20 + r];
            }
        }
    }

    const int lane = tid & 63;
    const int wid  = tid >> 6;
    const int sw   = lane / 20;              // 0..2 active, 3 idle
    const int ll   = lane - sw * 20;         // 0..19 row/col id within subgroup
    const int sg   = wid * 3 + (sw < 3 ? sw : 0);
    const int e    = chunk * 12 + sg;
    if (sw == 3 || e >= NE) return;          // no __syncthreads after this point

    const float gj   = sgR[ll];              // gammaR_j for this lane's column
    const float gamj = 0.5f * (sgL[ll] + gj);
    const float E    = fmaf((float)e, 6.0f / 99.0f, -3.0f);

    // build column ll of A
    f32x2 col[H_N];
    #pragma unroll
    for (int i = 0; i < H_N; ++i) {
        float hv = Hcm[ll * 20 + i];
        col[i].x = (i == ll) ? (E - hv) : (-hv);
        col[i].y = (i == ll) ? gamj : 0.0f;
    }

    f32x2* const myStage = (f32x2*)&stage[sg][0];

    // ---- in-place Gauss-Jordan, fully unrolled (static reg indices) ----
    #pragma unroll
    for (int k = 0; k < H_N; ++k) {
        // every lane publishes its element k: stage[sg][i] = M[k][i]
        myStage[ll] = col[k];                // one ds_write_b64, whole wave
        __builtin_amdgcn_wave_barrier();
        f32x4 q[10];
        #pragma unroll
        for (int qq = 0; qq < 10; ++qq) q[qq] = stage[sg][qq];
        __builtin_amdgcn_wave_barrier();

        // pivot = s_k = M[k][k]; p = 1/pivot (complex reciprocal)
        const float ykx = (k & 1) ? q[k >> 1].z : q[k >> 1].x;
        const float yky = (k & 1) ? q[k >> 1].w : q[k >> 1].y;
        const float den = fmaf(ykx, ykx, yky * yky);
        const float inv = __builtin_amdgcn_rcpf(den);
        const float px  =  ykx * inv;
        const float py  = -yky * inv;

        // t = col[k] * p ; lane k uses tu = [1+px, py] (e_k substitution folded)
        const float tx  = col[k].x * px - col[k].y * py;
        const float ty  = col[k].x * py + col[k].y * px;
        const bool  isk = (ll == k);
        f32x2 tu; tu.x = isk ? (1.0f + px) : tx;  tu.y = isk ? py : ty;
        f32x2 fk; fk.x = isk ? px : tx;           fk.y = isk ? py : ty;

        // col[i] -= y[i]*tu, with y[i] = sigma * s_i, sigma = -1 for i<k
        #pragma unroll
        for (int i = 0; i < H_N; ++i) {
            if (i == k) continue;
            f32x2 s = (i & 1) ? __builtin_shufflevector(q[i >> 1], q[i >> 1], 2, 3)
                              : __builtin_shufflevector(q[i >> 1], q[i >> 1], 0, 1);
            if (i < k) upd_neg(col[i], s, tu);
            else       upd_pos(col[i], s, tu);
        }
        col[k] = fk;
    }

    // ---- epilogue: T partial + diag Im, subgroup reduce, store ----
    float tv = 0.0f, dv = 0.0f;
    #pragma unroll
    for (int i = 0; i < H_N; ++i) {
        float aa = fmaf(col[i].x, col[i].x, col[i].y * col[i].y);
        tv = fmaf(sgL[i], aa, tv);
        dv = (i == ll) ? col[i].y : dv;
    }
    tv *= gj;

    #pragma unroll
    for (int d = 16; d >= 1; d >>= 1) {
        float t2 = __shfl(tv, lane + d, 64);
        float d2 = __shfl(dv, lane + d, 64);
        if (ll + d < 20) { tv += t2; dv += d2; }
    }
    if (ll == 0) {
        out[T_OFF + b * NE + e] = __log10f(fmaxf(tv, 1e-16f));
        out[D_OFF + b * NE + e] = __log10f(fmaxf(-dv, 1e-16f));
    }
}

extern "C" void kernel_launch(void* const* d_in, const int* in_sizes, int n_in,
                              void* d_out, int out_size, void* d_ws, size_t ws_size,
                              hipStream_t stream) {
    const float* tri = (const float*)d_in[0];
    const float* gL  = (const float*)d_in[1];
    const float* gR  = (const float*)d_in[2];
    float* out = (float*)d_out;
    negf_all<<<1024 * 9, 256, 0, stream>>>(tri, gL, gR, out);
}

// Round 8
// 101.529 us; speedup vs baseline: 1.0148x; 1.0148x over previous
//
#include <hip/hip_runtime.h>

// DNA transport NEGF: per (b,e) invert A = (E*I - H) + i*diag(0.5*(gL+gR)),
// DOS = -Im tr(Gr), T = sum_ij gL_i gR_j |Gr_ij|^2, plus H scatter output.
//
// Lane j of a 20-lane subgroup owns column j of A (in-place Gauss-Jordan ->
// same registers end as column j of Gr). 3 subgroups/wave, 4 waves/block.
// Grid = 1024 batches x 9 chunks (12 energies each, flat).
//
// SYMMETRY BROADCAST (R3): no-pivot GJ on complex-symmetric A preserves
// M[i][j] = sigma*M[j][i] (sigma=-1 iff exactly one of i,j processed), so
// the pivot column is readable from each lane's own col[k]: one wave-wide
// ds_write_b64 + 10 broadcast ds_read_b128 per step. Signs fold into FMAs.
//
// FORCED v_pk_fma_f32 (R5): inline asm, signs + [tu.y,tu.x] swap folded into
// VOP3P op_sel/neg modifiers -> exactly 2 v_pk_fma_f32 per row.
//
// INTERLEAVED READS (R7): R4-R6 showed the allocator voluntarily parks
// col[]/q[] in AGPRs (VGPR_Count 36-52 even with a 256-reg budget) and pays
// v_accvgpr shuttles around every asm use -- ~95 of ~148 VALU instr/step.
// Loading all 10 broadcast quads up front made the live set ~90 regs. Fix:
// read each quad just before its 2 row-updates (pivot quad first, reused).
// Live set ~56 regs -> fits the frugal arch allocation, no AGPR traffic.
// DS count unchanged. Also fk.y==tu.y (one cndmask saved).
//
// R1 lesson: ds_bpermute (40 DS/step) loses. R2 lesson: starving the
// allocator remats y[] from LDS -> DS-bound.
//
// No pivoting: imag(x^* A x) > 0 for all leading blocks => pivots bounded
// below by min_i 0.5(gL_i+gR_i). Stable in fp32 (R0-R6: absmax <= 3.9e-3).

typedef float f32x2 __attribute__((ext_vector_type(2)));
typedef float f32x4 __attribute__((ext_vector_type(4)));

#define H_N   20
#define NE    100
#define T_OFF 0
#define D_OFF 102400
#define H_OFF 204800

__device__ __forceinline__ int triIdx(int i, int j) {  // i <= j, row-major triu
    return i * H_N - ((i * (i - 1)) >> 1) + (j - i);
}

// col -= (+s)*tu : lo: c.x += s.y*tu.y - s.x*tu.x ; hi: c.y += -s.y*tu.x - s.x*tu.y
__device__ __forceinline__ void upd_pos(f32x2& c, f32x2 s, f32x2 tu) {
    asm("v_pk_fma_f32 %0, %1, %2, %0 op_sel:[1,1,0] op_sel_hi:[1,0,1] neg_hi:[1,0,0]\n\t"
        "v_pk_fma_f32 %0, %1, %2, %0 op_sel_hi:[0,1,1] neg_lo:[1,0,0] neg_hi:[1,0,0]"
        : "+v"(c) : "v"(s), "v"(tu));
}

// col -= (-s)*tu : lo: c.x += -s.y*tu.y + s.x*tu.x ; hi: c.y += s.y*tu.x + s.x*tu.y
__device__ __forceinline__ void upd_neg(f32x2& c, f32x2 s, f32x2 tu) {
    asm("v_pk_fma_f32 %0, %1, %2, %0 op_sel:[1,1,0] op_sel_hi:[1,0,1] neg_lo:[1,0,0]\n\t"
        "v_pk_fma_f32 %0, %1, %2, %0 op_sel_hi:[0,1,1]"
        : "+v"(c) : "v"(s), "v"(tu));
}

__global__ __launch_bounds__(256, 2)
void negf_all(const float* __restrict__ tri,
              const float* __restrict__ GL,
              const float* __restrict__ GR,
              float* __restrict__ out)
{
    __shared__ float Hcm[400];          // column-major: Hcm[c*20 + r] = H[r][c]
    __shared__ float sgL[H_N], sgR[H_N];
    __shared__ f32x4 stage[12][10];     // per-subgroup pivot-column broadcast

    const int blk   = blockIdx.x;
    const int b     = blk / 9;
    const int chunk = blk - b * 9;
    const int tid   = threadIdx.x;

    // ---- stage H (column-major) + gammas into LDS ----
    const float* triB = tri + b * 210;
    #pragma unroll
    for (int u0 = 0; u0 < 2; ++u0) {
        int u = tid + u0 * 256;
        if (u < 400) {
            int c = u / 20, r = u - c * 20;
            int lo = r < c ? r : c;
            int hi = r < c ? c : r;
            Hcm[u] = triB[triIdx(lo, hi)];
        }
    }
    if (tid < H_N) {
        sgL[tid] = GL[b * H_N + tid];
        sgR[tid] = GR[b * H_N + tid];
    }
    __syncthreads();

    // ---- H output (row-major), exact copy of inputs; one block per b ----
    if (chunk == 0) {
        #pragma unroll
        for (int u0 = 0; u0 < 2; ++u0) {
            int u = tid + u0 * 256;
            if (u < 400) {
                int r = u / 20, c = u - r * 20;
                out[H_OFF + b * 400 + u] = Hcm[c * 20 + r];
            }
        }
    }

    const int lane = tid & 63;
    const int wid  = tid >> 6;
    const int sw   = lane / 20;              // 0..2 active, 3 idle
    const int ll   = lane - sw * 20;         // 0..19 row/col id within subgroup
    const int sg   = wid * 3 + (sw < 3 ? sw : 0);
    const int e    = chunk * 12 + sg;
    if (sw == 3 || e >= NE) return;          // no __syncthreads after this point

    const float gj   = sgR[ll];              // gammaR_j for this lane's column
    const float gamj = 0.5f * (sgL[ll] + gj);
    const float E    = fmaf((float)e, 6.0f / 99.0f, -3.0f);

    // build column ll of A
    f32x2 col[H_N];
    #pragma unroll
    for (int i = 0; i < H_N; ++i) {
        float hv = Hcm[ll * 20 + i];
        col[i].x = (i == ll) ? (E - hv) : (-hv);
        col[i].y = (i == ll) ? gamj : 0.0f;
    }

    f32x2* const myStage = (f32x2*)&stage[sg][0];

    // ---- in-place Gauss-Jordan, fully unrolled (static reg indices) ----
    #pragma unroll
    for (int k = 0; k < H_N; ++k) {
        const int kq = k >> 1;
        // every lane publishes its element k: stage[sg][i] = M[k][i]
        myStage[ll] = col[k];                // one ds_write_b64, whole wave
        __builtin_amdgcn_wave_barrier();

        // pivot quad first: start the reciprocal chain immediately
        const f32x4 qp  = stage[sg][kq];
        const float ykx = (k & 1) ? qp.z : qp.x;
        const float yky = (k & 1) ? qp.w : qp.y;
        const float den = fmaf(ykx, ykx, yky * yky);
        const float inv = __builtin_amdgcn_rcpf(den);
        const float px  =  ykx * inv;
        const float py  = -yky * inv;

        // t = col[k] * p ; lane k uses tu = [1+px, py] (e_k substitution folded)
        const float tx  = col[k].x * px - col[k].y * py;
        const float ty  = col[k].x * py + col[k].y * px;
        const bool  isk = (ll == k);
        f32x2 tu; tu.x = isk ? (1.0f + px) : tx;  tu.y = isk ? py : ty;
        const float fkx = isk ? px : tx;     // note fk.y == tu.y

        // col[i] -= y[i]*tu, y[i] = sigma*s_i (sigma=-1 for i<k); quad-wise:
        // read each broadcast quad just before its two row-updates.
        #pragma unroll
        for (int qq = 0; qq < 10; ++qq) {
            const f32x4 qv = (qq == kq) ? qp : stage[sg][qq];
            const int i0 = 2 * qq, i1 = i0 + 1;
            f32x2 s0; s0.x = qv.x; s0.y = qv.y;
            f32x2 s1; s1.x = qv.z; s1.y = qv.w;
            if (i0 != k) {
                if (i0 < k) upd_neg(col[i0], s0, tu);
                else        upd_pos(col[i0], s0, tu);
            }
            if (i1 != k) {
                if (i1 < k) upd_neg(col[i1], s1, tu);
                else        upd_pos(col[i1], s1, tu);
            }
        }
        __builtin_amdgcn_wave_barrier();     // reads done before next k's write
        col[k].x = fkx;
        col[k].y = tu.y;
    }

    // ---- epilogue: T partial + diag Im, subgroup reduce, store ----
    float tv = 0.0f, dv = 0.0f;
    #pragma unroll
    for (int i = 0; i < H_N; ++i) {
        float aa = fmaf(col[i].x, col[i].x, col[i].y * col[i].y);
        tv = fmaf(sgL[i], aa, tv);
        dv = (i == ll) ? col[i].y : dv;
    }
    tv *= gj;

    #pragma unroll
    for (int d = 16; d >= 1; d >>= 1) {
        float t2 = __shfl(tv, lane + d, 64);
        float d2 = __shfl(dv, lane + d, 64);
        if (ll + d < 20) { tv += t2; dv += d2; }
    }
    if (ll == 0) {
        out[T_OFF + b * NE + e] = __log10f(fmaxf(tv, 1e-16f));
        out[D_OFF + b * NE + e] = __log10f(fmaxf(-dv, 1e-16f));
    }
}

extern "C" void kernel_launch(void* const* d_in, const int* in_sizes, int n_in,
                              void* d_out, int out_size, void* d_ws, size_t ws_size,
                              hipStream_t stream) {
    const float* tri = (const float*)d_in[0];
    const float* gL  = (const float*)d_in[1];
    const float* gR  = (const float*)d_in[2];
    float* out = (float*)d_out;
    negf_all<<<1024 * 9, 256, 0, stream>>>(tri, gL, gR, out);
}